// Round 2
// baseline (9844.732 us; speedup 1.0000x reference)
//
#include <hip/hip_runtime.h>
#include <stdint.h>

// ---------------- static problem config ----------------
#define S_TOT 21504
#define M_TOK 86016
// levels: (32,32) start 0, (64,64) start 1024, (128,128) start 5120

typedef __attribute__((ext_vector_type(8))) short bf16x8;
typedef __attribute__((ext_vector_type(4))) float f32x4;

__device__ __forceinline__ unsigned short f2b(float f) {
  union { float f; unsigned u; } v; v.f = f;
  unsigned r = v.u + 0x7FFFu + ((v.u >> 16) & 1u);
  return (unsigned short)(r >> 16);
}
__device__ __forceinline__ float b2f(unsigned short h) {
  union { unsigned u; float f; } v; v.u = ((unsigned)h) << 16;
  return v.f;
}

// ---------------- bf16 MFMA GEMM: C[M,N] = A[M,K] * Bt[N,K]^T + bias ----------------
// BM=BN=128, BK=32, 256 threads (4 waves, each owning a 64x64 quadrant).
// Register-staged global->LDS (no global_load_lds this round), next-tile reg prefetch.
template <int RELU, int OUT_BF16>
__global__ __launch_bounds__(256) void gemm_kernel(
    const unsigned short* __restrict__ A, const unsigned short* __restrict__ Bt,
    const float* __restrict__ bias, float* __restrict__ Cf,
    unsigned short* __restrict__ Cb, int N, int K) {
  __shared__ unsigned short Alds[128 * 32];
  __shared__ unsigned short Blds[128 * 32];
  const int tid = threadIdx.x;
  const int wave = tid >> 6, lane = tid & 63;
  const long m0 = (long)blockIdx.x * 128;
  const int n0 = blockIdx.y * 128;
  const int wm = (wave >> 1) * 64, wn = (wave & 1) * 64;

  f32x4 acc[4][4];
#pragma unroll
  for (int i = 0; i < 4; i++)
#pragma unroll
    for (int j = 0; j < 4; j++) acc[i][j] = (f32x4){0.f, 0.f, 0.f, 0.f};

  // chunk tid covers tile row tid>>2, k-range (tid&3)*8..+7 (16B); second chunk = +64 rows
  const int ar = tid >> 2, ak = (tid & 3) * 8;
  int brA = n0 + ar;      if (brA >= N) brA = N - 1;  // clamp OOB weight rows (never stored)
  int brB = n0 + ar + 64; if (brB >= N) brB = N - 1;
  const unsigned short* a0p = A + (m0 + ar) * (long)K + ak;
  const unsigned short* a1p = A + (m0 + ar + 64) * (long)K + ak;
  const unsigned short* b0p = Bt + (long)brA * K + ak;
  const unsigned short* b1p = Bt + (long)brB * K + ak;

  uint4 a0 = *(const uint4*)a0p;
  uint4 a1 = *(const uint4*)a1p;
  uint4 b0 = *(const uint4*)b0p;
  uint4 b1 = *(const uint4*)b1p;

  for (int k0 = 0; k0 < K; k0 += 32) {
    if (k0) __syncthreads();  // previous iteration's frag reads must finish
    ((uint4*)Alds)[tid] = a0;
    ((uint4*)Alds)[tid + 256] = a1;
    ((uint4*)Blds)[tid] = b0;
    ((uint4*)Blds)[tid + 256] = b1;
    if (k0 + 32 < K) {  // prefetch next K-tile into regs; latency hides under MFMA below
      a0 = *(const uint4*)(a0p + k0 + 32);
      a1 = *(const uint4*)(a1p + k0 + 32);
      b0 = *(const uint4*)(b0p + k0 + 32);
      b1 = *(const uint4*)(b1p + k0 + 32);
    }
    __syncthreads();

    const int kk = (lane >> 4) * 8;
    bf16x8 af[4], bq[4];
#pragma unroll
    for (int i = 0; i < 4; i++)
      af[i] = *(const bf16x8*)&Alds[(wm + i * 16 + (lane & 15)) * 32 + kk];
#pragma unroll
    for (int j = 0; j < 4; j++)
      bq[j] = *(const bf16x8*)&Blds[(wn + j * 16 + (lane & 15)) * 32 + kk];
#pragma unroll
    for (int i = 0; i < 4; i++)
#pragma unroll
      for (int j = 0; j < 4; j++)
        acc[i][j] = __builtin_amdgcn_mfma_f32_16x16x32_bf16(af[i], bq[j], acc[i][j], 0, 0, 0);
  }

  const int colb = lane & 15, rowb = (lane >> 4) * 4;
#pragma unroll
  for (int j = 0; j < 4; j++) {
    const int n = n0 + wn + j * 16 + colb;
    if (n < N) {
      const float bn = bias[n];
#pragma unroll
      for (int i = 0; i < 4; i++) {
#pragma unroll
        for (int r = 0; r < 4; r++) {
          const long m = m0 + wm + i * 16 + rowb + r;
          float v = acc[i][j][r] + bn;
          if (RELU) v = fmaxf(v, 0.f);
          if (OUT_BF16) Cb[m * N + n] = f2b(v);
          else Cf[m * N + n] = v;
        }
      }
    }
  }
}

// ---------------- weight transpose + bf16 convert: [L][K][N] -> [L][N][K] ----------------
__global__ void wtrans_kernel(const float* __restrict__ src, unsigned short* __restrict__ dst,
                              int K, int N) {
  __shared__ float t[32][33];
  const int tx = threadIdx.x, ty = threadIdx.y;
  const int n0 = blockIdx.x * 32, k0 = blockIdx.y * 32, l = blockIdx.z;
  src += (size_t)l * K * N;
  dst += (size_t)l * N * K;
#pragma unroll
  for (int i = 0; i < 4; i++) t[ty * 4 + i][tx] = src[(size_t)(k0 + ty * 4 + i) * N + n0 + tx];
  __syncthreads();
#pragma unroll
  for (int i = 0; i < 4; i++)
    dst[(size_t)(n0 + ty * 4 + i) * K + k0 + tx] = f2b(t[tx][ty * 4 + i]);
}

// ---------------- flatten [B,C,H,W] -> [B,HW,C]; src->outf(f32)+outb(b16), pos+lemb->posb ----
__global__ void flatten_kernel(const float* __restrict__ src, const float* __restrict__ pos,
                               const float* __restrict__ lemb, float* __restrict__ outf,
                               unsigned short* __restrict__ outb, unsigned short* __restrict__ posb,
                               int HW, int s0) {
  __shared__ float ts[32][33];
  __shared__ float tp[32][33];
  const int tx = threadIdx.x, ty = threadIdx.y;
  const int hw0 = blockIdx.x * 32, c0 = blockIdx.y * 32, b = blockIdx.z;
  const size_t ibase = ((size_t)b * 256 + c0) * HW + hw0;
#pragma unroll
  for (int i = 0; i < 4; i++) {
    ts[ty * 4 + i][tx] = src[ibase + (size_t)(ty * 4 + i) * HW + tx];
    tp[ty * 4 + i][tx] = pos[ibase + (size_t)(ty * 4 + i) * HW + tx];
  }
  __syncthreads();
#pragma unroll
  for (int i = 0; i < 4; i++) {
    const int sI = s0 + hw0 + ty * 4 + i, c = c0 + tx;
    const size_t o = ((size_t)b * S_TOT + sI) * 256 + c;
    const float sv = ts[tx][ty * 4 + i];
    outf[o] = sv;
    outb[o] = f2b(sv);
    posb[o] = f2b(tp[tx][ty * 4 + i] + lemb[c]);
  }
}

// ---------------- q = bf16(out_f32 + pos_b16) ----------------
__global__ __launch_bounds__(256) void addq_kernel(const float* __restrict__ of,
                                                   const unsigned short* __restrict__ pb,
                                                   unsigned short* __restrict__ qb) {
  const size_t i = (size_t)blockIdx.x * 256 + threadIdx.x;
  const float4 o = ((const float4*)of)[i];
  const ushort4 p = ((const ushort4*)pb)[i];
  ushort4 r;
  r.x = f2b(o.x + b2f(p.x));
  r.y = f2b(o.y + b2f(p.y));
  r.z = f2b(o.z + b2f(p.z));
  r.w = f2b(o.w + b2f(p.w));
  ((ushort4*)qb)[i] = r;
}

// ---------------- deformable attention sampling (all operands bf16) ----------------
// one block per (b,s); thread = (head = tid>>5, d = tid&31)
__global__ __launch_bounds__(256) void deform_kernel(const unsigned short* __restrict__ value,
                                                     const unsigned short* __restrict__ offs,
                                                     const unsigned short* __restrict__ aw,
                                                     unsigned short* __restrict__ attn) {
  const int bs = blockIdx.x;
  const int b = bs / S_TOT, s = bs - b * S_TOT;
  __shared__ float loff[192];
  __shared__ float law[96];
  const int tid = threadIdx.x;
  if (tid < 192) loff[tid] = b2f(offs[(size_t)bs * 192 + tid]);
  if (tid < 96) law[tid] = b2f(aw[(size_t)bs * 96 + tid]);
  __syncthreads();
  if (tid < 8) {  // per-head softmax over NL*NP=12
    float mx = -1e30f;
#pragma unroll
    for (int i = 0; i < 12; i++) mx = fmaxf(mx, law[tid * 12 + i]);
    float e[12], sm = 0.f;
#pragma unroll
    for (int i = 0; i < 12; i++) { e[i] = __expf(law[tid * 12 + i] - mx); sm += e[i]; }
    const float r = 1.f / sm;
#pragma unroll
    for (int i = 0; i < 12; i++) law[tid * 12 + i] = e[i] * r;
  }
  __syncthreads();

  const int h = tid >> 5, d = tid & 31;
  float rx, ry;
  {
    if (s < 1024) { const int li = s; rx = ((li & 31) + 0.5f) * (1.f / 32); ry = ((li >> 5) + 0.5f) * (1.f / 32); }
    else if (s < 5120) { const int li = s - 1024; rx = ((li & 63) + 0.5f) * (1.f / 64); ry = ((li >> 6) + 0.5f) * (1.f / 64); }
    else { const int li = s - 5120; rx = ((li & 127) + 0.5f) * (1.f / 128); ry = ((li >> 7) + 0.5f) * (1.f / 128); }
  }
  const int wl_[3] = {32, 64, 128};
  const int st_[3] = {0, 1024, 5120};
  float acc = 0.f;
#pragma unroll
  for (int lvl = 0; lvl < 3; lvl++) {
    const int wl = wl_[lvl];
    const float fwl = (float)wl;
    const unsigned short* vb = value + ((size_t)b * S_TOT + st_[lvl]) * 256 + h * 32 + d;
#pragma unroll
    for (int p = 0; p < 4; p++) {
      const int oi = ((h * 3 + lvl) * 4 + p) * 2;
      const float lx = rx + loff[oi] / fwl;      // match ref FP order: ref + off/wh
      const float ly = ry + loff[oi + 1] / fwl;
      const float x = lx * fwl - 0.5f, y = ly * fwl - 0.5f;
      const float xf = floorf(x), yf = floorf(y);
      const int x0 = (int)xf, y0 = (int)yf;
      const float fx = x - xf, fy = y - yf;
      const bool xv0 = (x0 >= 0) & (x0 < wl), xv1 = (x0 + 1 >= 0) & (x0 + 1 < wl);
      const bool yv0 = (y0 >= 0) & (y0 < wl), yv1 = (y0 + 1 >= 0) & (y0 + 1 < wl);
      float v00 = 0.f, v01 = 0.f, v10 = 0.f, v11 = 0.f;
      if (yv0 & xv0) v00 = b2f(vb[(size_t)(y0 * wl + x0) * 256]);
      if (yv0 & xv1) v01 = b2f(vb[(size_t)(y0 * wl + x0 + 1) * 256]);
      if (yv1 & xv0) v10 = b2f(vb[(size_t)((y0 + 1) * wl + x0) * 256]);
      if (yv1 & xv1) v11 = b2f(vb[(size_t)((y0 + 1) * wl + x0 + 1) * 256]);
      const float w = law[h * 12 + lvl * 4 + p];
      acc += w * (v00 * (1.f - fx) * (1.f - fy) + v01 * fx * (1.f - fy) +
                  v10 * (1.f - fx) * fy + v11 * fx * fy);
    }
  }
  attn[(size_t)bs * 256 + h * 32 + d] = f2b(acc);
}

// ---------------- residual + layernorm (one wave per token); r is bf16 ----------------
__global__ __launch_bounds__(256) void resln_kernel(const float* __restrict__ x,
                                                    const unsigned short* __restrict__ r,
                                                    const float* __restrict__ g,
                                                    const float* __restrict__ bta,
                                                    float* __restrict__ of,
                                                    unsigned short* __restrict__ ob) {
  const int t = blockIdx.x * 4 + (threadIdx.x >> 6);
  const int lane = threadIdx.x & 63;
  const size_t base = (size_t)t * 256;
  const float4 xv = ((const float4*)(x + base))[lane];
  const ushort4 rv = ((const ushort4*)(r + base))[lane];
  const float v0 = xv.x + b2f(rv.x), v1 = xv.y + b2f(rv.y);
  const float v2 = xv.z + b2f(rv.z), v3 = xv.w + b2f(rv.w);
  float sm = v0 + v1 + v2 + v3;
#pragma unroll
  for (int o = 32; o > 0; o >>= 1) sm += __shfl_xor(sm, o);
  const float mean = sm * (1.f / 256.f);
  const float d0 = v0 - mean, d1 = v1 - mean, d2 = v2 - mean, d3 = v3 - mean;
  float vs = d0 * d0 + d1 * d1 + d2 * d2 + d3 * d3;
#pragma unroll
  for (int o = 32; o > 0; o >>= 1) vs += __shfl_xor(vs, o);
  const float inv = rsqrtf(vs * (1.f / 256.f) + 1e-5f);
  const int c = lane * 4;
  const float o0 = d0 * inv * g[c] + bta[c];
  const float o1 = d1 * inv * g[c + 1] + bta[c + 1];
  const float o2 = d2 * inv * g[c + 2] + bta[c + 2];
  const float o3 = d3 * inv * g[c + 3] + bta[c + 3];
  ((float4*)(of + base))[lane] = make_float4(o0, o1, o2, o3);
  if (ob) {
    ushort4 u;
    u.x = f2b(o0); u.y = f2b(o1); u.z = f2b(o2); u.w = f2b(o3);
    ((ushort4*)(ob + base))[lane] = u;
  }
}

// ---------------- host ----------------
extern "C" void kernel_launch(void* const* d_in, const int* in_sizes, int n_in,
                              void* d_out, int out_size, void* d_ws, size_t ws_size,
                              hipStream_t stream) {
  (void)in_sizes; (void)n_in; (void)out_size;
  const float* src0 = (const float*)d_in[0];
  const float* pos0 = (const float*)d_in[1];
  const float* src1 = (const float*)d_in[2];
  const float* pos1 = (const float*)d_in[3];
  const float* src2 = (const float*)d_in[4];
  const float* pos2 = (const float*)d_in[5];
  const float* lemb = (const float*)d_in[6];
  const float* Wv = (const float*)d_in[7];   const float* bv = (const float*)d_in[8];
  const float* Wo = (const float*)d_in[9];   const float* bo = (const float*)d_in[10];
  const float* Wa = (const float*)d_in[11];  const float* ba = (const float*)d_in[12];
  const float* Wout = (const float*)d_in[13]; const float* bout = (const float*)d_in[14];
  const float* ln1g = (const float*)d_in[15]; const float* ln1b = (const float*)d_in[16];
  const float* W1 = (const float*)d_in[17];  const float* b1 = (const float*)d_in[18];
  const float* W2 = (const float*)d_in[19];  const float* b2 = (const float*)d_in[20];
  const float* ln2g = (const float*)d_in[21]; const float* ln2b = (const float*)d_in[22];

  const size_t M = M_TOK;
  // ---- workspace layout (317,030,400 bytes) ----
  // buf16   : M*256 bf16  (value / attn_out / ff2-out)          44,040,192 B
  // overlay : 176,160,768 B = max(h[M*1024 b16], q+offs+aw+attn)
  // out_b16 : M*256 bf16                                         44,040,192 B
  // pos_b16 : M*256 bf16                                         44,040,192 B
  // wt      : 4,374,528 bf16 (all transposed weights)             8,749,056 B
  const size_t NEED = 44040192ull + 176160768ull + 44040192ull + 44040192ull + 8749056ull;
  if (ws_size < NEED) return;  // clean absmax-fail instead of a memory fault (diagnostic)

  char* ws = (char*)d_ws;
  unsigned short* buf16 = (unsigned short*)ws;      ws += 44040192ull;
  char* ov = ws;                                    ws += 176160768ull;
  unsigned short* q_b16 = (unsigned short*)ov;
  unsigned short* offs_b16 = (unsigned short*)(ov + (size_t)M * 256 * 2);
  unsigned short* aw_b16 = (unsigned short*)(ov + (size_t)M * 448 * 2);
  unsigned short* attn_b16 = (unsigned short*)(ov + (size_t)M * 544 * 2);
  unsigned short* h_b16 = (unsigned short*)ov;  // clobbers q/offs/aw/attn (dead by then)
  unsigned short* out_b16 = (unsigned short*)ws;    ws += 44040192ull;
  unsigned short* pos_b16 = (unsigned short*)ws;    ws += 44040192ull;
  unsigned short* wt = (unsigned short*)ws;

  unsigned short* wtv = wt;                 // [6][256][256]
  unsigned short* wto = wt + 393216;        // [6][192][256]
  unsigned short* wta = wt + 688128;        // [6][96][256]
  unsigned short* wtw = wt + 835584;        // [6][256][256]
  unsigned short* wt1 = wt + 1228800;       // [6][1024][256]
  unsigned short* wt2 = wt + 2801664;       // [6][256][1024]

  float* out_f32 = (float*)d_out;  // residual stream lives in d_out (fully rewritten per call)

  const dim3 b32(32, 8);
  wtrans_kernel<<<dim3(8, 8, 6), b32, 0, stream>>>(Wv, wtv, 256, 256);
  wtrans_kernel<<<dim3(6, 8, 6), b32, 0, stream>>>(Wo, wto, 256, 192);
  wtrans_kernel<<<dim3(3, 8, 6), b32, 0, stream>>>(Wa, wta, 256, 96);
  wtrans_kernel<<<dim3(8, 8, 6), b32, 0, stream>>>(Wout, wtw, 256, 256);
  wtrans_kernel<<<dim3(32, 8, 6), b32, 0, stream>>>(W1, wt1, 256, 1024);
  wtrans_kernel<<<dim3(8, 32, 6), b32, 0, stream>>>(W2, wt2, 1024, 256);

  flatten_kernel<<<dim3(32, 8, 4), b32, 0, stream>>>(src0, pos0, lemb, out_f32, out_b16, pos_b16, 1024, 0);
  flatten_kernel<<<dim3(128, 8, 4), b32, 0, stream>>>(src1, pos1, lemb + 256, out_f32, out_b16, pos_b16, 4096, 1024);
  flatten_kernel<<<dim3(512, 8, 4), b32, 0, stream>>>(src2, pos2, lemb + 512, out_f32, out_b16, pos_b16, 16384, 5120);

  for (int l = 0; l < 6; l++) {
    addq_kernel<<<21504, 256, 0, stream>>>(out_f32, pos_b16, q_b16);
    gemm_kernel<0, 1><<<dim3(672, 2), 256, 0, stream>>>(out_b16, wtv + l * 65536, bv + l * 256, nullptr, buf16, 256, 256);
    gemm_kernel<0, 1><<<dim3(672, 2), 256, 0, stream>>>(q_b16, wto + l * 49152, bo + l * 192, nullptr, offs_b16, 192, 256);
    gemm_kernel<0, 1><<<dim3(672, 1), 256, 0, stream>>>(q_b16, wta + l * 24576, ba + l * 96, nullptr, aw_b16, 96, 256);
    deform_kernel<<<M_TOK, 256, 0, stream>>>(buf16, offs_b16, aw_b16, attn_b16);
    gemm_kernel<0, 1><<<dim3(672, 2), 256, 0, stream>>>(attn_b16, wtw + l * 65536, bout + l * 256, nullptr, buf16, 256, 256);
    resln_kernel<<<21504, 256, 0, stream>>>(out_f32, buf16, ln1g + l * 256, ln1b + l * 256, out_f32, out_b16);
    gemm_kernel<1, 1><<<dim3(672, 8), 256, 0, stream>>>(out_b16, wt1 + l * 262144, b1 + l * 1024, nullptr, h_b16, 1024, 256);
    gemm_kernel<0, 1><<<dim3(672, 2), 256, 0, stream>>>(h_b16, wt2 + l * 262144, b2 + l * 256, nullptr, buf16, 256, 1024);
    resln_kernel<<<21504, 256, 0, stream>>>(out_f32, buf16, ln2g + l * 256, ln2b + l * 256, out_f32, (l == 5) ? nullptr : out_b16);
  }
}

// Round 3
// 3348.611 us; speedup vs baseline: 2.9399x; 2.9399x over previous
//
#include <hip/hip_runtime.h>
#include <stdint.h>

// ---------------- static problem config ----------------
#define S_TOT 21504
#define M_TOK 86016
// levels: (32,32) start 0, (64,64) start 1024, (128,128) start 5120

typedef __attribute__((ext_vector_type(8))) short bf16x8;
typedef __attribute__((ext_vector_type(4))) float f32x4;

__device__ __forceinline__ unsigned short f2b(float f) {
  union { float f; unsigned u; } v; v.f = f;
  unsigned r = v.u + 0x7FFFu + ((v.u >> 16) & 1u);
  return (unsigned short)(r >> 16);
}
__device__ __forceinline__ float b2f(unsigned short h) {
  union { unsigned u; float f; } v; v.u = ((unsigned)h) << 16;
  return v.f;
}
__device__ __forceinline__ float blo(unsigned u) {
  union { unsigned u; float f; } v; v.u = u << 16; return v.f;
}
__device__ __forceinline__ float bhi(unsigned u) {
  union { unsigned u; float f; } v; v.u = u & 0xffff0000u; return v.f;
}

// ---------------- bf16 MFMA GEMM: C[M,N] = A[M,K] * Bt[N,K]^T + bias ----------------
// BM=BN=128, BK=32, 256 threads (4 waves, each owning a 64x64 quadrant).
// Register-staged global->LDS, next-tile reg prefetch. (Known-good from round 2.)
template <int RELU, int OUT_BF16>
__global__ __launch_bounds__(256) void gemm_kernel(
    const unsigned short* __restrict__ A, const unsigned short* __restrict__ Bt,
    const float* __restrict__ bias, float* __restrict__ Cf,
    unsigned short* __restrict__ Cb, int N, int K) {
  __shared__ unsigned short Alds[128 * 32];
  __shared__ unsigned short Blds[128 * 32];
  const int tid = threadIdx.x;
  const int wave = tid >> 6, lane = tid & 63;
  const long m0 = (long)blockIdx.x * 128;
  const int n0 = blockIdx.y * 128;
  const int wm = (wave >> 1) * 64, wn = (wave & 1) * 64;

  f32x4 acc[4][4];
#pragma unroll
  for (int i = 0; i < 4; i++)
#pragma unroll
    for (int j = 0; j < 4; j++) acc[i][j] = (f32x4){0.f, 0.f, 0.f, 0.f};

  const int ar = tid >> 2, ak = (tid & 3) * 8;
  int brA = n0 + ar;      if (brA >= N) brA = N - 1;
  int brB = n0 + ar + 64; if (brB >= N) brB = N - 1;
  const unsigned short* a0p = A + (m0 + ar) * (long)K + ak;
  const unsigned short* a1p = A + (m0 + ar + 64) * (long)K + ak;
  const unsigned short* b0p = Bt + (long)brA * K + ak;
  const unsigned short* b1p = Bt + (long)brB * K + ak;

  uint4 a0 = *(const uint4*)a0p;
  uint4 a1 = *(const uint4*)a1p;
  uint4 b0 = *(const uint4*)b0p;
  uint4 b1 = *(const uint4*)b1p;

  for (int k0 = 0; k0 < K; k0 += 32) {
    if (k0) __syncthreads();
    ((uint4*)Alds)[tid] = a0;
    ((uint4*)Alds)[tid + 256] = a1;
    ((uint4*)Blds)[tid] = b0;
    ((uint4*)Blds)[tid + 256] = b1;
    if (k0 + 32 < K) {
      a0 = *(const uint4*)(a0p + k0 + 32);
      a1 = *(const uint4*)(a1p + k0 + 32);
      b0 = *(const uint4*)(b0p + k0 + 32);
      b1 = *(const uint4*)(b1p + k0 + 32);
    }
    __syncthreads();

    const int kk = (lane >> 4) * 8;
    bf16x8 af[4], bq[4];
#pragma unroll
    for (int i = 0; i < 4; i++)
      af[i] = *(const bf16x8*)&Alds[(wm + i * 16 + (lane & 15)) * 32 + kk];
#pragma unroll
    for (int j = 0; j < 4; j++)
      bq[j] = *(const bf16x8*)&Blds[(wn + j * 16 + (lane & 15)) * 32 + kk];
#pragma unroll
    for (int i = 0; i < 4; i++)
#pragma unroll
      for (int j = 0; j < 4; j++)
        acc[i][j] = __builtin_amdgcn_mfma_f32_16x16x32_bf16(af[i], bq[j], acc[i][j], 0, 0, 0);
  }

  const int colb = lane & 15, rowb = (lane >> 4) * 4;
#pragma unroll
  for (int j = 0; j < 4; j++) {
    const int n = n0 + wn + j * 16 + colb;
    if (n < N) {
      const float bn = bias[n];
#pragma unroll
      for (int i = 0; i < 4; i++) {
#pragma unroll
        for (int r = 0; r < 4; r++) {
          const long m = m0 + wm + i * 16 + rowb + r;
          float v = acc[i][j][r] + bn;
          if (RELU) v = fmaxf(v, 0.f);
          if (OUT_BF16) Cb[m * N + n] = f2b(v);
          else Cf[m * N + n] = v;
        }
      }
    }
  }
}

// ---------------- weight transpose + bf16 convert: [L][K][N] -> [L][N][K] ----------------
__global__ void wtrans_kernel(const float* __restrict__ src, unsigned short* __restrict__ dst,
                              int K, int N) {
  __shared__ float t[32][33];
  const int tx = threadIdx.x, ty = threadIdx.y;
  const int n0 = blockIdx.x * 32, k0 = blockIdx.y * 32, l = blockIdx.z;
  src += (size_t)l * K * N;
  dst += (size_t)l * N * K;
#pragma unroll
  for (int i = 0; i < 4; i++) t[ty * 4 + i][tx] = src[(size_t)(k0 + ty * 4 + i) * N + n0 + tx];
  __syncthreads();
#pragma unroll
  for (int i = 0; i < 4; i++)
    dst[(size_t)(n0 + ty * 4 + i) * K + k0 + tx] = f2b(t[tx][ty * 4 + i]);
}

// ---------------- flatten [B,C,H,W] -> [B,HW,C]; writes out f32/b16, pos b16, q b16 ----
__global__ void flatten_kernel(const float* __restrict__ src, const float* __restrict__ pos,
                               const float* __restrict__ lemb, float* __restrict__ outf,
                               unsigned short* __restrict__ outb, unsigned short* __restrict__ posb,
                               unsigned short* __restrict__ qb, int HW, int s0) {
  __shared__ float ts[32][33];
  __shared__ float tp[32][33];
  const int tx = threadIdx.x, ty = threadIdx.y;
  const int hw0 = blockIdx.x * 32, c0 = blockIdx.y * 32, b = blockIdx.z;
  const size_t ibase = ((size_t)b * 256 + c0) * HW + hw0;
#pragma unroll
  for (int i = 0; i < 4; i++) {
    ts[ty * 4 + i][tx] = src[ibase + (size_t)(ty * 4 + i) * HW + tx];
    tp[ty * 4 + i][tx] = pos[ibase + (size_t)(ty * 4 + i) * HW + tx];
  }
  __syncthreads();
#pragma unroll
  for (int i = 0; i < 4; i++) {
    const int sI = s0 + hw0 + ty * 4 + i, c = c0 + tx;
    const size_t o = ((size_t)b * S_TOT + sI) * 256 + c;
    const float sv = ts[tx][ty * 4 + i];
    const unsigned short pb = f2b(tp[tx][ty * 4 + i] + lemb[c]);
    outf[o] = sv;
    outb[o] = f2b(sv);
    posb[o] = pb;
    qb[o] = f2b(sv + b2f(pb));  // q = out + pos (matches prior addq numerics)
  }
}

// ---------------- deformable attention sampling v2 ----------------
// One 64-lane wave per token; block = 4 tokens. Stage 1: lanes<8 softmax per head.
// Stage 2: 96 tap descriptors (clamped idx4, aw-folded weight4) cooperatively into LDS.
// Stage 3: gather, lane = (head = lane>>3, 4 channels = (lane&7)*4), uint2 loads.
__global__ __launch_bounds__(256) void deform_kernel(const unsigned short* __restrict__ value,
                                                     const unsigned short* __restrict__ offs,
                                                     const unsigned short* __restrict__ aw,
                                                     unsigned short* __restrict__ attn) {
  __shared__ float law[4][96];
  __shared__ uint4 didx[4][96];
  __shared__ float4 dwt[4][96];
  const int tid = threadIdx.x;
  const int wv = tid >> 6, lane = tid & 63;
  const int bs = blockIdx.x * 4 + wv;
  const int b = bs / S_TOT, s = bs - b * S_TOT;

  if (lane < 8) {  // per-head softmax over NL*NP=12
    const unsigned short* ap = aw + (size_t)bs * 96 + lane * 12;
    const uint2 p0 = *(const uint2*)ap;
    const uint2 p1 = *(const uint2*)(ap + 4);
    const uint2 p2 = *(const uint2*)(ap + 8);
    float a[12] = {blo(p0.x), bhi(p0.x), blo(p0.y), bhi(p0.y),
                   blo(p1.x), bhi(p1.x), blo(p1.y), bhi(p1.y),
                   blo(p2.x), bhi(p2.x), blo(p2.y), bhi(p2.y)};
    float mx = a[0];
#pragma unroll
    for (int i = 1; i < 12; i++) mx = fmaxf(mx, a[i]);
    float e[12], sm = 0.f;
#pragma unroll
    for (int i = 0; i < 12; i++) { e[i] = __expf(a[i] - mx); sm += e[i]; }
    const float r = 1.f / sm;
#pragma unroll
    for (int i = 0; i < 12; i++) law[wv][lane * 12 + i] = e[i] * r;
  }
  __syncthreads();

  float rx, ry;
  {
    if (s < 1024) { const int li = s; rx = ((li & 31) + 0.5f) * (1.f / 32); ry = ((li >> 5) + 0.5f) * (1.f / 32); }
    else if (s < 5120) { const int li = s - 1024; rx = ((li & 63) + 0.5f) * (1.f / 64); ry = ((li >> 6) + 0.5f) * (1.f / 64); }
    else { const int li = s - 5120; rx = ((li & 127) + 0.5f) * (1.f / 128); ry = ((li >> 7) + 0.5f) * (1.f / 128); }
  }

  for (int ti = lane; ti < 96; ti += 64) {
    const int h = ti / 12;
    const int rem = ti - h * 12;
    const int lvl = rem >> 2;
    const int wl = 32 << lvl;
    const float fwl = (float)wl;
    const int start = (lvl == 0) ? 0 : ((lvl == 1) ? 1024 : 5120);
    const unsigned op = *(const unsigned*)(offs + (size_t)bs * 192 + 2 * ti);
    const float ox = blo(op), oy = bhi(op);
    const float x = (rx + ox / fwl) * fwl - 0.5f;   // matches ref FP order
    const float y = (ry + oy / fwl) * fwl - 0.5f;
    const float xf = floorf(x), yf = floorf(y);
    const int x0 = (int)xf, y0 = (int)yf;
    const float fx = x - xf, fy = y - yf;
    const bool xv0 = (x0 >= 0) & (x0 < wl), xv1 = (x0 + 1 >= 0) & (x0 + 1 < wl);
    const bool yv0 = (y0 >= 0) & (y0 < wl), yv1 = (y0 + 1 >= 0) & (y0 + 1 < wl);
    const int x0c = min(max(x0, 0), wl - 1), x1c = min(max(x0 + 1, 0), wl - 1);
    const int y0c = min(max(y0, 0), wl - 1), y1c = min(max(y0 + 1, 0), wl - 1);
    const float w = law[wv][ti];
    float4 w4;
    w4.x = (xv0 & yv0) ? w * (1.f - fx) * (1.f - fy) : 0.f;
    w4.y = (xv1 & yv0) ? w * fx * (1.f - fy) : 0.f;
    w4.z = (xv0 & yv1) ? w * (1.f - fx) * fy : 0.f;
    w4.w = (xv1 & yv1) ? w * fx * fy : 0.f;
    const int base = ((b * S_TOT + start) << 8) + h * 32;  // element offset into value
    uint4 iv;
    iv.x = base + (unsigned)(y0c * wl + x0c) * 256u;
    iv.y = base + (unsigned)(y0c * wl + x1c) * 256u;
    iv.z = base + (unsigned)(y1c * wl + x0c) * 256u;
    iv.w = base + (unsigned)(y1c * wl + x1c) * 256u;
    didx[wv][ti] = iv;
    dwt[wv][ti] = w4;
  }
  __syncthreads();

  const int h = lane >> 3, c = (lane & 7) * 4;
  const uint4* ip = &didx[wv][h * 12];
  const float4* wp = &dwt[wv][h * 12];
  float a0 = 0.f, a1 = 0.f, a2 = 0.f, a3 = 0.f;
#pragma unroll 4
  for (int t = 0; t < 12; t++) {
    const uint4 iv = ip[t];
    const float4 w4 = wp[t];
    const uint2 q00 = *(const uint2*)(value + iv.x + c);
    const uint2 q01 = *(const uint2*)(value + iv.y + c);
    const uint2 q10 = *(const uint2*)(value + iv.z + c);
    const uint2 q11 = *(const uint2*)(value + iv.w + c);
    a0 += w4.x * blo(q00.x) + w4.y * blo(q01.x) + w4.z * blo(q10.x) + w4.w * blo(q11.x);
    a1 += w4.x * bhi(q00.x) + w4.y * bhi(q01.x) + w4.z * bhi(q10.x) + w4.w * bhi(q11.x);
    a2 += w4.x * blo(q00.y) + w4.y * blo(q01.y) + w4.z * blo(q10.y) + w4.w * blo(q11.y);
    a3 += w4.x * bhi(q00.y) + w4.y * bhi(q01.y) + w4.z * bhi(q10.y) + w4.w * bhi(q11.y);
  }
  uint2 o;
  o.x = (unsigned)f2b(a0) | ((unsigned)f2b(a1) << 16);
  o.y = (unsigned)f2b(a2) | ((unsigned)f2b(a3) << 16);
  *(uint2*)(attn + (size_t)bs * 256 + h * 32 + c) = o;
}

// ---------------- residual + layernorm (one wave per token); r is bf16 ----------------
// Optionally also emits q = bf16(out + pos) for the next layer (folds old addq kernel).
__global__ __launch_bounds__(256) void resln_kernel(const float* __restrict__ x,
                                                    const unsigned short* __restrict__ r,
                                                    const float* __restrict__ g,
                                                    const float* __restrict__ bta,
                                                    float* __restrict__ of,
                                                    unsigned short* __restrict__ ob,
                                                    const unsigned short* __restrict__ pos,
                                                    unsigned short* __restrict__ qb) {
  const int t = blockIdx.x * 4 + (threadIdx.x >> 6);
  const int lane = threadIdx.x & 63;
  const size_t base = (size_t)t * 256;
  const float4 xv = ((const float4*)(x + base))[lane];
  const ushort4 rv = ((const ushort4*)(r + base))[lane];
  const float v0 = xv.x + b2f(rv.x), v1 = xv.y + b2f(rv.y);
  const float v2 = xv.z + b2f(rv.z), v3 = xv.w + b2f(rv.w);
  float sm = v0 + v1 + v2 + v3;
#pragma unroll
  for (int o = 32; o > 0; o >>= 1) sm += __shfl_xor(sm, o);
  const float mean = sm * (1.f / 256.f);
  const float d0 = v0 - mean, d1 = v1 - mean, d2 = v2 - mean, d3 = v3 - mean;
  float vs = d0 * d0 + d1 * d1 + d2 * d2 + d3 * d3;
#pragma unroll
  for (int o = 32; o > 0; o >>= 1) vs += __shfl_xor(vs, o);
  const float inv = rsqrtf(vs * (1.f / 256.f) + 1e-5f);
  const int c = lane * 4;
  const float o0 = d0 * inv * g[c] + bta[c];
  const float o1 = d1 * inv * g[c + 1] + bta[c + 1];
  const float o2 = d2 * inv * g[c + 2] + bta[c + 2];
  const float o3 = d3 * inv * g[c + 3] + bta[c + 3];
  ((float4*)(of + base))[lane] = make_float4(o0, o1, o2, o3);
  if (ob) {
    ushort4 u;
    u.x = f2b(o0); u.y = f2b(o1); u.z = f2b(o2); u.w = f2b(o3);
    ((ushort4*)(ob + base))[lane] = u;
  }
  if (qb) {
    const ushort4 pv = ((const ushort4*)(pos + base))[lane];
    ushort4 u;
    u.x = f2b(o0 + b2f(pv.x)); u.y = f2b(o1 + b2f(pv.y));
    u.z = f2b(o2 + b2f(pv.z)); u.w = f2b(o3 + b2f(pv.w));
    ((ushort4*)(qb + base))[lane] = u;
  }
}

// ---------------- host ----------------
extern "C" void kernel_launch(void* const* d_in, const int* in_sizes, int n_in,
                              void* d_out, int out_size, void* d_ws, size_t ws_size,
                              hipStream_t stream) {
  (void)in_sizes; (void)n_in; (void)out_size;
  const float* src0 = (const float*)d_in[0];
  const float* pos0 = (const float*)d_in[1];
  const float* src1 = (const float*)d_in[2];
  const float* pos1 = (const float*)d_in[3];
  const float* src2 = (const float*)d_in[4];
  const float* pos2 = (const float*)d_in[5];
  const float* lemb = (const float*)d_in[6];
  const float* Wv = (const float*)d_in[7];   const float* bv = (const float*)d_in[8];
  const float* Wo = (const float*)d_in[9];   const float* bo = (const float*)d_in[10];
  const float* Wa = (const float*)d_in[11];  const float* ba = (const float*)d_in[12];
  const float* Wout = (const float*)d_in[13]; const float* bout = (const float*)d_in[14];
  const float* ln1g = (const float*)d_in[15]; const float* ln1b = (const float*)d_in[16];
  const float* W1 = (const float*)d_in[17];  const float* b1 = (const float*)d_in[18];
  const float* W2 = (const float*)d_in[19];  const float* b2 = (const float*)d_in[20];
  const float* ln2g = (const float*)d_in[21]; const float* ln2b = (const float*)d_in[22];

  const size_t M = M_TOK;
  const size_t NEED = 44040192ull + 176160768ull + 44040192ull + 44040192ull + 8749056ull;
  if (ws_size < NEED) return;

  char* ws = (char*)d_ws;
  unsigned short* buf16 = (unsigned short*)ws;      ws += 44040192ull;
  char* ov = ws;                                    ws += 176160768ull;
  unsigned short* q_b16 = (unsigned short*)ov;
  unsigned short* offs_b16 = (unsigned short*)(ov + (size_t)M * 256 * 2);
  unsigned short* aw_b16 = (unsigned short*)(ov + (size_t)M * 448 * 2);
  unsigned short* attn_b16 = (unsigned short*)(ov + (size_t)M * 544 * 2);
  unsigned short* h_b16 = (unsigned short*)ov;  // clobbers q/offs/aw/attn (dead by then)
  unsigned short* out_b16 = (unsigned short*)ws;    ws += 44040192ull;
  unsigned short* pos_b16 = (unsigned short*)ws;    ws += 44040192ull;
  unsigned short* wt = (unsigned short*)ws;

  unsigned short* wtv = wt;                 // [6][256][256]
  unsigned short* wto = wt + 393216;        // [6][192][256]
  unsigned short* wta = wt + 688128;        // [6][96][256]
  unsigned short* wtw = wt + 835584;        // [6][256][256]
  unsigned short* wt1 = wt + 1228800;       // [6][1024][256]
  unsigned short* wt2 = wt + 2801664;       // [6][256][1024]

  float* out_f32 = (float*)d_out;  // residual stream lives in d_out

  const dim3 b32(32, 8);
  wtrans_kernel<<<dim3(8, 8, 6), b32, 0, stream>>>(Wv, wtv, 256, 256);
  wtrans_kernel<<<dim3(6, 8, 6), b32, 0, stream>>>(Wo, wto, 256, 192);
  wtrans_kernel<<<dim3(3, 8, 6), b32, 0, stream>>>(Wa, wta, 256, 96);
  wtrans_kernel<<<dim3(8, 8, 6), b32, 0, stream>>>(Wout, wtw, 256, 256);
  wtrans_kernel<<<dim3(32, 8, 6), b32, 0, stream>>>(W1, wt1, 256, 1024);
  wtrans_kernel<<<dim3(8, 32, 6), b32, 0, stream>>>(W2, wt2, 1024, 256);

  flatten_kernel<<<dim3(32, 8, 4), b32, 0, stream>>>(src0, pos0, lemb, out_f32, out_b16, pos_b16, q_b16, 1024, 0);
  flatten_kernel<<<dim3(128, 8, 4), b32, 0, stream>>>(src1, pos1, lemb + 256, out_f32, out_b16, pos_b16, q_b16, 4096, 1024);
  flatten_kernel<<<dim3(512, 8, 4), b32, 0, stream>>>(src2, pos2, lemb + 512, out_f32, out_b16, pos_b16, q_b16, 16384, 5120);

  for (int l = 0; l < 6; l++) {
    gemm_kernel<0, 1><<<dim3(672, 2), 256, 0, stream>>>(out_b16, wtv + l * 65536, bv + l * 256, nullptr, buf16, 256, 256);
    gemm_kernel<0, 1><<<dim3(672, 2), 256, 0, stream>>>(q_b16, wto + l * 49152, bo + l * 192, nullptr, offs_b16, 192, 256);
    gemm_kernel<0, 1><<<dim3(672, 1), 256, 0, stream>>>(q_b16, wta + l * 24576, ba + l * 96, nullptr, aw_b16, 96, 256);
    deform_kernel<<<21504, 256, 0, stream>>>(buf16, offs_b16, aw_b16, attn_b16);
    gemm_kernel<0, 1><<<dim3(672, 2), 256, 0, stream>>>(attn_b16, wtw + l * 65536, bout + l * 256, nullptr, buf16, 256, 256);
    resln_kernel<<<21504, 256, 0, stream>>>(out_f32, buf16, ln1g + l * 256, ln1b + l * 256, out_f32, out_b16, nullptr, nullptr);
    gemm_kernel<1, 1><<<dim3(672, 8), 256, 0, stream>>>(out_b16, wt1 + l * 262144, b1 + l * 1024, nullptr, h_b16, 1024, 256);
    gemm_kernel<0, 1><<<dim3(672, 2), 256, 0, stream>>>(h_b16, wt2 + l * 262144, b2 + l * 256, nullptr, buf16, 256, 1024);
    resln_kernel<<<21504, 256, 0, stream>>>(out_f32, buf16, ln2g + l * 256, ln2b + l * 256, out_f32,
                                            (l == 5) ? nullptr : out_b16,
                                            (l == 5) ? nullptr : pos_b16,
                                            (l == 5) ? nullptr : q_b16);
  }
}